// Round 12
// baseline (186.704 us; speedup 1.0000x reference)
//
#include <hip/hip_runtime.h>
#include <cstdint>
#include <cstddef>

// GRU cell fused: B=16384, I=H=512.
// ws: X bf16 [16384][1024] @0 (32 MB), Wrz bf16 [1024][1024] @32M (2 MB),
//     Wih bf16 [512][1024] @34M (1 MB).
// gru_fused: BM=128 x BN=64, BK=32, 3-buffer COUNTED-vmcnt pipeline (T4):
// 2-tile lookahead, vmcnt never drains to 0 in the loop.  Raw s_barrier
// paired with empty asm memory fences (s_barrier builtin is NOT an IR
// fence; fence prevents ds_read/STAGE hoisting across it — m152 race).
// Loops NOT unrolled (compile-time + icache safety).
// Evidence: r2/r3/r11 all 72-77us @ 27-30% MfmaUtil across 3 schedules
// that share the per-K-step vmcnt(0) drain; m233/m218 say counted vmcnt
// is the lever.  Launch bounds (256,2): (256,4) spilled acc (r10).

typedef __attribute__((ext_vector_type(8))) __bf16 bf16x8;
typedef __attribute__((ext_vector_type(4))) float f32x4;
typedef __attribute__((ext_vector_type(8))) unsigned short u16x8;

__device__ __forceinline__ unsigned short f2bf(float f) {
    unsigned u = __builtin_bit_cast(unsigned, f);
    return (unsigned short)((u + 0x7fffu + ((u >> 16) & 1u)) >> 16);  // RNE
}

__global__ void prep_x(const float* __restrict__ inp, const float* __restrict__ hid,
                       unsigned short* __restrict__ X) {
    int t = blockIdx.x * 256 + threadIdx.x;   // 16384*128 threads
    int b = t >> 7;
    int j = (t & 127) << 3;                   // 0..1016, step 8
    const float* src = (j < 512) ? (inp + (size_t)b * 512 + j)
                                 : (hid + (size_t)b * 512 + (j - 512));
    u16x8 o;
#pragma unroll
    for (int e = 0; e < 8; ++e) o[e] = f2bf(src[e]);
    *reinterpret_cast<u16x8*>(X + (size_t)b * 1024 + j) = o;
}

__global__ void prep_w(const float* __restrict__ Wg, const float* __restrict__ Wi,
                       const float* __restrict__ Wh,
                       unsigned short* __restrict__ Wrz, unsigned short* __restrict__ Wih) {
    int t = blockIdx.x * 256 + threadIdx.x;   // 196608 threads
    if (t < 131072) {                         // W_gate: 1M elements, 8/thread
        const float* src = Wg + (size_t)t * 8;
        u16x8 o;
#pragma unroll
        for (int e = 0; e < 8; ++e) o[e] = f2bf(src[e]);
        *reinterpret_cast<u16x8*>(Wrz + (size_t)t * 8) = o;
    } else {                                  // Wih[n][k] = k<512 ? Wi[n][k] : Wh[n][k-512]
        int u = t - 131072;                   // 512 rows x 128 chunks
        int n = u >> 7;
        int k = (u & 127) << 3;
        const float* src = (k < 512) ? (Wi + (size_t)n * 512 + k)
                                     : (Wh + (size_t)n * 512 + (k - 512));
        u16x8 o;
#pragma unroll
        for (int e = 0; e < 8; ++e) o[e] = f2bf(src[e]);
        *reinterpret_cast<u16x8*>(Wih + (size_t)n * 1024 + k) = o;
    }
}

__device__ __forceinline__ void gload16(const void* g, void* l) {
    __builtin_amdgcn_global_load_lds(
        (const __attribute__((address_space(1))) void*)g,
        (__attribute__((address_space(3))) void*)l, 16, 0, 0);
}

// BK=32 tiles: rows of 32 bf16 (64 B = 4 chunks of 16 B).  Logical chunk ch of
// row r stored at physical chunk (ch ^ ((r>>1)&3)); per 16-lane read phase
// 2 lanes/bank = free.  Staged via pre-swizzled global source (involution).
__device__ __forceinline__ bf16x8 ldfrag32(const unsigned short* base, int row, int c0) {
    const char* p = (const char*)base + row * 64 + ((c0 ^ ((row >> 1) & 3)) << 4);
    return *reinterpret_cast<const bf16x8*>(p);
}

#define WAITV(n) asm volatile("s_waitcnt vmcnt(" #n ")" ::: "memory")
#define FENCE()  asm volatile("" ::: "memory")

__global__ __launch_bounds__(256, 2) void gru_fused(
        const unsigned short* __restrict__ X,    // [16384][1024] bf16
        const unsigned short* __restrict__ Wr,   // [512][1024] bf16
        const unsigned short* __restrict__ Wz,   // [512][1024] bf16
        const unsigned short* __restrict__ Wih,  // [512][1024] bf16
        const float* __restrict__ hid,           // [16384][512]
        const float* __restrict__ bgate,         // [1024]
        const float* __restrict__ bi,            // [512]
        const float* __restrict__ bh,            // [512]
        float* __restrict__ out) {               // [16384][512]
    // Per buffer (20 KB): X[128x32] @0, R[64x32] @8KB, Z @12KB, W @16KB.
    __shared__ unsigned short lds[3][10240];     // 60 KB -> 2 blocks/CU

    const int tid = threadIdx.x;
    const int lane = tid & 63;
    const int wid = tid >> 6;
    const int wm = wid >> 1, wn = wid & 1;       // 2x2 waves; wave = 64x32 per gate
    const int bid = blockIdx.x;
    const int bn = bid & 7;                      // col tile -> XCD (weights L2-resident)
    const int bm = bid >> 3;                     // 128 row tiles

    // --- staging source (pre-swizzled): thread covers chunk (row=tid>>2, c=tid&3),
    //     storing logical chunk lc = (tid&3) ^ ((tid>>3)&3).
    const int srow = tid >> 2;                   // 0..63
    const int lc = (tid & 3) ^ ((tid >> 3) & 3);
    const char* gX0 = (const char*)X   + ((size_t)(bm * 128 + srow) * 1024 + lc * 8) * 2;
    const char* gX1 = gX0 + 64 * 2048;           // rows 64..127 (same lc)
    const char* gR  = (const char*)Wr  + ((size_t)(bn * 64 + srow) * 1024 + lc * 8) * 2;
    const char* gZ  = (const char*)Wz  + ((size_t)(bn * 64 + srow) * 1024 + lc * 8) * 2;
    const char* gW  = (const char*)Wih + ((size_t)(bn * 64 + srow) * 1024 + lc * 8) * 2;

    f32x4 accR[4][2], accZ[4][2], accI[4][2], accH[4][2];
#pragma unroll
    for (int i = 0; i < 4; ++i)
#pragma unroll
        for (int j = 0; j < 2; ++j) {
            accR[i][j] = (f32x4){0.f, 0.f, 0.f, 0.f};
            accZ[i][j] = (f32x4){0.f, 0.f, 0.f, 0.f};
            accI[i][j] = (f32x4){0.f, 0.f, 0.f, 0.f};
            accH[i][j] = (f32x4){0.f, 0.f, 0.f, 0.f};
        }

    const int ra = wm * 64 + (lane & 15);        // A-frag base row
    const int rb = wn * 32 + (lane & 15);        // B-frag base row (out col)
    const int c0 = lane >> 4;                    // k-chunk 0..3

    // 5 global_load_lds per thread per tile; LDS dest is wave-linear.
#define STAGE(t, b) {                                                  \
        char* lp = (char*)lds[b] + tid * 16;                           \
        gload16(gX0 + (t) * 64, lp);                                   \
        gload16(gX1 + (t) * 64, lp + 4096);                            \
        gload16(gR  + (t) * 64, lp + 8192);                            \
        gload16(gZ  + (t) * 64, lp + 12288);                           \
        gload16(gW  + (t) * 64, lp + 16384); }

#define MFMA8(ACC, B0, B1)                                                            \
    ACC[0][0] = __builtin_amdgcn_mfma_f32_16x16x32_bf16(a0, B0, ACC[0][0], 0, 0, 0); \
    ACC[1][0] = __builtin_amdgcn_mfma_f32_16x16x32_bf16(a1, B0, ACC[1][0], 0, 0, 0); \
    ACC[2][0] = __builtin_amdgcn_mfma_f32_16x16x32_bf16(a2, B0, ACC[2][0], 0, 0, 0); \
    ACC[3][0] = __builtin_amdgcn_mfma_f32_16x16x32_bf16(a3, B0, ACC[3][0], 0, 0, 0); \
    ACC[0][1] = __builtin_amdgcn_mfma_f32_16x16x32_bf16(a0, B1, ACC[0][1], 0, 0, 0); \
    ACC[1][1] = __builtin_amdgcn_mfma_f32_16x16x32_bf16(a1, B1, ACC[1][1], 0, 0, 0); \
    ACC[2][1] = __builtin_amdgcn_mfma_f32_16x16x32_bf16(a2, B1, ACC[2][1], 0, 0, 0); \
    ACC[3][1] = __builtin_amdgcn_mfma_f32_16x16x32_bf16(a3, B1, ACC[3][1], 0, 0, 0);

#define COMPUTE(b, ACC3) {                                             \
        const unsigned short* bp = lds[b];                             \
        bf16x8 a0 = ldfrag32(bp, ra,      c0);                         \
        bf16x8 a1 = ldfrag32(bp, ra + 16, c0);                         \
        bf16x8 a2 = ldfrag32(bp, ra + 32, c0);                         \
        bf16x8 a3 = ldfrag32(bp, ra + 48, c0);                         \
        bf16x8 b0 = ldfrag32(bp + 4096, rb, c0);                       \
        bf16x8 b1 = ldfrag32(bp + 4096, rb + 16, c0);                  \
        MFMA8(accR, b0, b1)                                            \
        b0 = ldfrag32(bp + 6144, rb, c0);                              \
        b1 = ldfrag32(bp + 6144, rb + 16, c0);                         \
        MFMA8(accZ, b0, b1)                                            \
        b0 = ldfrag32(bp + 8192, rb, c0);                              \
        b1 = ldfrag32(bp + 8192, rb + 16, c0);                         \
        MFMA8(ACC3, b0, b1) }

    // Pipeline advance: publish tile t+1, refill freed buffer with t+3.
    // vmcnt: steady state has tiles t+1,t+2 (10 loads) + just-issued t+3
    // (5) = 15 outstanding; WAITV(10) = tile t+1 landed.  Tail: t=29 ->
    // 10 outstanding, WAITV(5) = tile 30; t=30 -> 5, WAITV(0) = tile 31.
#define PIPE(t) {                                                      \
        __builtin_amdgcn_s_barrier();  /* all waves done reading t%3 */\
        FENCE();                                                       \
        if ((t) + 3 < 32) STAGE((t) + 3, (t) % 3)                      \
        if ((t) < 29)       { WAITV(10); }                             \
        else if ((t) == 29) { WAITV(5); }                              \
        else                { WAITV(0); }                              \
        __builtin_amdgcn_s_barrier();  /* tile t+1 visible to all  */  \
        FENCE();                                                       \
    }

    // --- prologue: stage tiles 0,1,2 (15 in flight), wait tile 0 only ---
    STAGE(0, 0)
    STAGE(1, 1)
    STAGE(2, 2)
    WAITV(10);
    __builtin_amdgcn_s_barrier();
    FENCE();

#pragma unroll 1
    for (int t = 0; t < 16; ++t) {               // k in [0,512): i_gate
        COMPUTE(t % 3, accI)
        PIPE(t)
    }
#pragma unroll 1
    for (int t = 16; t < 32; ++t) {              // k in [512,1024): h_gate
        COMPUTE(t % 3, accH)
        if (t < 31) PIPE(t)
    }
#undef PIPE
#undef COMPUTE
#undef MFMA8
#undef STAGE

    // --- fused GRU epilogue ---
    const int colb = bn * 64 + wn * 32 + (lane & 15);
    const int rowb = bm * 128 + wm * 64 + ((lane >> 4) << 2);
#pragma unroll
    for (int ni = 0; ni < 2; ++ni) {
        const int n = colb + ni * 16;
        const float bgr = bgate[n];
        const float bgz = bgate[512 + n];
        const float bii = bi[n];
        const float bhh = bh[n];
#pragma unroll
        for (int mi = 0; mi < 4; ++mi) {
#pragma unroll
            for (int r = 0; r < 4; ++r) {
                const int m = rowb + mi * 16 + r;
                const size_t off = (size_t)m * 512 + n;
                float rg = accR[mi][ni][r] + bgr;
                rg = 1.f / (1.f + __expf(-rg));
                float zg = accZ[mi][ni][r] + bgz;
                zg = 1.f / (1.f + __expf(-zg));
                float x = accI[mi][ni][r] + bii + rg * (accH[mi][ni][r] + bhh);
                x = fminf(fmaxf(x, -15.f), 15.f);
                const float e = __expf(2.f * x);
                const float ng = (e - 1.f) / (e + 1.f);   // tanh(x)
                out[off] = ng + zg * (hid[off] - ng);     // (1-z)*n + z*h
            }
        }
    }
}

extern "C" void kernel_launch(void* const* d_in, const int* in_sizes, int n_in,
                              void* d_out, int out_size, void* d_ws, size_t ws_size,
                              hipStream_t stream) {
    const float* inp = (const float*)d_in[0];
    const float* hid = (const float*)d_in[1];
    const float* Wg  = (const float*)d_in[2];
    const float* bg  = (const float*)d_in[3];
    const float* Wi  = (const float*)d_in[4];
    const float* bi  = (const float*)d_in[5];
    const float* Wh  = (const float*)d_in[6];
    const float* bh  = (const float*)d_in[7];
    float* out = (float*)d_out;

    unsigned short* X   = (unsigned short*)d_ws;
    unsigned short* Wrz = (unsigned short*)((char*)d_ws + 33554432);
    unsigned short* Wih = (unsigned short*)((char*)d_ws + 33554432 + 2097152);

    prep_x<<<8192, 256, 0, stream>>>(inp, hid, X);
    prep_w<<<768, 256, 0, stream>>>(Wg, Wi, Wh, Wrz, Wih);
    gru_fused<<<1024, 256, 0, stream>>>(X, Wrz, Wrz + 512 * 1024, Wih,
                                        hid, bg, bi, bh, out);
}